// Round 6
// baseline (2514.230 us; speedup 1.0000x reference)
//
#include <hip/hip_runtime.h>
#include <cstdint>
#include <cstddef>

// GroupPointNet: FPS -> kNN(20) -> gf=(dp,grouped) -> 3x(conv1x1+lrelu+BN) -> max_k
// B=4, N=8192, M=2048, K=20, C=64. All f32.
// R12: fpsknn (R11, unchanged) + ONE fused tail kernel replacing convB/stats2/stats3/out.
//      256 blocks x 256 thr, 3 software grid barriers (agent-scope acq_rel counter +
//      acquire spin; all blocks trivially co-resident). Launches 5 -> 3; saves ~2 full
//      u2t re-read passes' launch overhead (~250us of dispatch/ramp).

#define B_ 4
#define N_ 8192
#define M_ 2048
#define K_ 20
#define BMK (B_*M_*K_)   // 163840
#define EPS_ 1e-5f
#define TILE_ 1024
#define PERS 248

typedef unsigned long long ull;
typedef float f32x2 __attribute__((ext_vector_type(2)));

// ---------- helpers ----------
__device__ __forceinline__ ull packkey(float d, int idx) {
  unsigned int bb = __float_as_uint(d);
  bb ^= (bb & 0x80000000u) ? 0xFFFFFFFFu : 0x80000000u;  // order-preserving map
  return ((ull)bb << 32) | (unsigned int)idx;
}
__device__ __forceinline__ float keymaxf(ull k) {
  unsigned int hb = (unsigned int)(k >> 32);
  unsigned int fb = (hb & 0x80000000u) ? (hb ^ 0x80000000u) : ~hb;
  return __uint_as_float(fb);
}
// keys sorted ascending; caller guarantees key < keys[19]
__device__ __forceinline__ void insert20(ull* keys, ull key) {
#pragma unroll
  for (int i = 19; i > 0; --i) {
    ull lo = keys[i-1];
    keys[i] = (key < lo) ? lo : ((key < keys[i]) ? key : keys[i]);
  }
  keys[0] = (key < keys[0]) ? key : keys[0];
}

#define DPPMAXU(V, CTRL) {                                                           \
    unsigned int nh = (unsigned int)__builtin_amdgcn_update_dpp(                     \
        (int)V, (int)V, CTRL, 0xF, 0xF, false);                                      \
    V = (nh > V) ? nh : V; }

// ---------- fused fps + knn + stats1 (R11, unchanged) ----------
__global__ __launch_bounds__(512)
void fpsknn_kernel(const float* __restrict__ p, float* __restrict__ p1,
                   float* __restrict__ gfp, const float* __restrict__ W1,
                   float* __restrict__ stats, int* __restrict__ prog) {
  __shared__ union {
    struct { float4 pts4[N_]; unsigned int slotsv[2][8]; int idxsel[2]; } f;  // 131144 B
    struct { float4 tile[TILE_]; ull mk[8*32*20]; float bs[128]; } k;         // 57856 B
  } sm;
  const int tid = threadIdx.x;

  if (blockIdx.x < B_) {
    // ================= FPS role (R7 verbatim) ==========
#pragma clang fp contract(off)
    const int b = blockIdx.x;
    const float* pb = p + (size_t)b * (N_*3);
    float* p1b = p1 + (size_t)b * (M_*3);
    float4* pts4 = sm.f.pts4;
    const int wv = tid >> 6;                   // wave 0..7
    const int base = tid * 16;                 // 16 points per thread, 8 float2 pairs
    f32x2 X[8], Y[8], Z[8], D[8];
#pragma unroll
    for (int j = 0; j < 8; ++j) {
      int i = base + 2*j;
      float x0 = pb[i*3+0], y0 = pb[i*3+1], z0 = pb[i*3+2];
      float x1 = pb[i*3+3], y1 = pb[i*3+4], z1 = pb[i*3+5];
      X[j] = (f32x2){x0, x1};
      Y[j] = (f32x2){y0, y1};
      Z[j] = (f32x2){z0, z1};
      D[j] = (f32x2){1e10f, 1e10f};
      pts4[i]   = make_float4(x0, y0, z0, 0.f);
      pts4[i+1] = make_float4(x1, y1, z1, 0.f);
    }
    if (tid < 2) sm.f.idxsel[tid] = 0x7FFFFFFF;
    float qx = pb[0], qy = pb[1], qz = pb[2];  // idx0 = 0
    if (tid == 0) { p1b[0] = qx; p1b[1] = qy; p1b[2] = qz; }
    __syncthreads();
    for (int t = 1; t < M_; ++t) {
      const int cur = t & 1;
      f32x2 q2x = (f32x2){qx, qx};
      f32x2 q2y = (f32x2){qy, qy};
      f32x2 q2z = (f32x2){qz, qz};
      f32x2 tmx = (f32x2){-1.f, -1.f};
#pragma unroll
      for (int j = 0; j < 8; ++j) {
        // plain vector ops (contract off): per-lane rounding identical to XLA
        f32x2 dx = X[j] - q2x;
        f32x2 dy = Y[j] - q2y;
        f32x2 dz = Z[j] - q2z;
        f32x2 s = (dx*dx + dy*dy) + dz*dz;
        f32x2 dj = __builtin_elementwise_min(D[j], s);
        D[j] = dj;
        tmx = __builtin_elementwise_max(tmx, dj);
      }
      float tm = fmaxf(tmx.x, tmx.y);
      const unsigned int tmb = __float_as_uint(tm);  // d>=0: bit order == float order
      unsigned int hv = tmb;
      DPPMAXU(hv, 0x111)  // row_shr:1
      DPPMAXU(hv, 0x112)  // row_shr:2
      DPPMAXU(hv, 0x114)  // row_shr:4
      DPPMAXU(hv, 0x118)  // row_shr:8
      DPPMAXU(hv, 0x142)  // row_bcast:15
      DPPMAXU(hv, 0x143)  // row_bcast:31
      if ((tid & 63) == 63) sm.f.slotsv[cur][wv] = hv;
      __syncthreads();                         // barrier 1: slots ready
      if (tid == 0) sm.f.idxsel[cur ^ 1] = 0x7FFFFFFF;   // prep slot for t+1
      unsigned int g = sm.f.slotsv[cur][0];
#pragma unroll
      for (int j = 1; j < 8; ++j) { unsigned int s2 = sm.f.slotsv[cur][j]; g = (s2 > g) ? s2 : g; }
      if (tmb == g) {                          // holder(s) of the max
        int fj = 0x7FFFFFFF;
#pragma unroll
        for (int j = 7; j >= 0; --j) {         // descending so lowest index wins
          if (__float_as_uint(D[j].y) == g) fj = base + 2*j + 1;
          if (__float_as_uint(D[j].x) == g) fj = base + 2*j;
        }
        atomicMin(&sm.f.idxsel[cur], fj);      // global first-index tie-break
      }
      __syncthreads();                         // barrier 2: index final
      int sel = sm.f.idxsel[cur];
      sel = __builtin_amdgcn_readfirstlane(sel);
      float4 qv = pts4[sel];                   // broadcast ds_read_b128
      qx = qv.x; qy = qv.y; qz = qv.z;
      if (tid == 0) {
        p1b[t*3+0] = qx; p1b[t*3+1] = qy; p1b[t*3+2] = qz;
        if ((t & 63) == 63)
          __hip_atomic_store(&prog[b], t, __ATOMIC_RELEASE, __HIP_MEMORY_SCOPE_AGENT);
      }
    }
    if (tid == 0)
      __hip_atomic_store(&prog[b], M_, __ATOMIC_RELEASE, __HIP_MEMORY_SCOPE_AGENT);
    return;
  }

  // ================= kNN + stats1 role (persistent consumer) ======================
  float4* tile = sm.k.tile;
  ull* mk = sm.k.mk;
  float* gfl = (float*)sm.k.tile;              // overlays tile after the scan phase
  float* bs = sm.k.bs;
  for (int ord = (int)blockIdx.x - B_; ord < 1024; ord += PERS) {
    const int b = ord & 3;                     // readiness-ordered chunks per block
    const int q0 = (ord >> 2) * 8;
    if (tid == 0) {
      while (__hip_atomic_load(&prog[b], __ATOMIC_ACQUIRE, __HIP_MEMORY_SCOPE_AGENT) < q0 + 7)
        __builtin_amdgcn_s_sleep(16);
    }
    __syncthreads();
    { int pv = __hip_atomic_load(&prog[b], __ATOMIC_ACQUIRE, __HIP_MEMORY_SCOPE_AGENT);
      asm volatile("" :: "v"(pv)); }           // per-thread acquire, kept live

    const int ql = (tid >> 5) & 7;             // query within block (tid<256 active)
    const int part = tid & 31;
    const int m = q0 + ql;
    const float* pb = p + (size_t)b*(N_*3);
    const float* qp_ = p1 + ((size_t)b*M_ + m)*3;
    float qx = qp_[0], qy = qp_[1], qz = qp_[2];
    float qq = __fadd_rn(__fadd_rn(__fmul_rn(qx,qx), __fmul_rn(qy,qy)), __fmul_rn(qz,qz));
    ull keys[20];
#pragma unroll
    for (int i = 0; i < 20; ++i) keys[i] = 0xFF8000007FFFFFFFull;  // pack(+inf, INT_MAX)
    float maxf = __uint_as_float(0x7F800000u);  // +inf
    for (int t0 = 0; t0 < N_; t0 += TILE_) {
      __syncthreads();                          // also guards gfl/tile reuse across chunks
      for (int i = tid; i < TILE_; i += 512) {
        float x = pb[(t0+i)*3+0], y = pb[(t0+i)*3+1], z = pb[(t0+i)*3+2];
        float pp = __fadd_rn(__fadd_rn(__fmul_rn(x,x), __fmul_rn(y,y)), __fmul_rn(z,z));
        tile[i] = make_float4(x, y, z, pp);
      }
      __syncthreads();
      if (tid < 256) {
        const int sbase = part * 32;
        for (int s = 0; s < 32; ++s) {
          int ss = sbase + ((s + part) & 31);   // bank skew across parts
          float4 pt = tile[ss];
          float qp = fmaf(pt.z, qz, fmaf(pt.y, qy, __fmul_rn(pt.x, qx)));
          float d = __fsub_rn(__fadd_rn(qq, pt.w), __fmul_rn(2.0f, qp));
          if (d <= maxf) {
            ull key = packkey(d, t0 + ss);
            if (key < keys[19]) { insert20(keys, key); maxf = keymaxf(keys[19]); }
          }
        }
      }
    }
    if (tid < 256) {
      ull* myslot = &mk[(ql*32 + part)*20];
#pragma unroll
      for (int i = 0; i < 20; ++i) myslot[i] = keys[i];
    }
    __syncthreads();
    if (tid < 256 && part == 0) {   // leader merges 32x20 sorted lists
      for (int pp2 = 1; pp2 < 32; ++pp2) {
        const ull* os = &mk[(ql*32 + pp2)*20];
        for (int i = 0; i < 20; ++i) {
          ull k = os[i];
          if (k >= keys[19]) break;    // sorted -> rest can't enter
          insert20(keys, k);
        }
      }
      ull* myslot = &mk[(ql*32)*20];
#pragma unroll
      for (int i = 0; i < 20; ++i) myslot[i] = keys[i];
    }
    __syncthreads();
    // gf write (global planes) + LDS stash for the stats1 tail
    for (int w = tid; w < 8*K_; w += 512) {
      int ql2 = w / K_;
      int kk = w - ql2*K_;
      ull key = mk[ql2*32*20 + kk];
      int idx = (int)(unsigned int)(key & 0xFFFFFFFFu);
      float gx = pb[idx*3+0], gy = pb[idx*3+1], gz = pb[idx*3+2];
      int m2 = q0 + ql2;
      const float* qv = p1 + ((size_t)b*M_ + m2)*3;
      size_t col = ((size_t)(b*M_ + m2))*K_ + kk;
      float d0 = __fsub_rn(gx, qv[0]);
      float d1 = __fsub_rn(gy, qv[1]);
      float d2 = __fsub_rn(gz, qv[2]);
      gfp[0*BMK + col] = d0;
      gfp[1*BMK + col] = d1;
      gfp[2*BMK + col] = d2;
      gfp[3*BMK + col] = gx;
      gfp[4*BMK + col] = gy;
      gfp[5*BMK + col] = gz;
      gfl[w*6+0] = d0; gfl[w*6+1] = d1; gfl[w*6+2] = d2;
      gfl[w*6+3] = gx; gfl[w*6+4] = gy; gfl[w*6+5] = gz;
    }
    __syncthreads();
    // stats1 tail: 8 grps x 64 lanes(=channels), 20 cols each (same fmaf sequence)
    {
      const int lane = tid & 63;
      const int grp = tid >> 6;
      float w1r[6];
#pragma unroll
      for (int c = 0; c < 6; ++c) w1r[c] = W1[lane*6 + c];
      float acc = 0.f, accq = 0.f;
      for (int cc = 0; cc < 20; ++cc) {
        const float* gv = &gfl[(grp*20 + cc)*6];
        float y = __fmul_rn(w1r[0], gv[0]);
#pragma unroll
        for (int c = 1; c < 6; ++c) y = fmaf(w1r[c], gv[c], y);
        float u = (y >= 0.f) ? y : 0.2f*y;
        acc += u;
        accq = fmaf(u, u, accq);
      }
      if (tid < 128) bs[tid] = 0.f;
      __syncthreads();
      atomicAdd(&bs[lane], acc);
      atomicAdd(&bs[64+lane], accq);
      __syncthreads();
      if (tid < 128) atomicAdd(&stats[tid], bs[tid]);
    }
  }
}

// BN coefficient replication (bit-identical to the old finalize_kernel)
__device__ __forceinline__ void bn_coeff(const float* __restrict__ st,
                                         const float* __restrict__ g,
                                         const float* __restrict__ bb,
                                         int o, float& A, float& C) {
  const float inv = 1.0f / (float)BMK;
  float mean = st[o] * inv;
  float var  = st[64+o] * inv - mean*mean;
  float a = g[o] / sqrtf(var + EPS_);
  A = a;
  C = fmaf(-a, mean, bb[o]);
}

// software grid barrier: all blocks co-resident (256 blocks x 4 waves << capacity)
__device__ __forceinline__ void gridbar(int* c, int expected) {
  __syncthreads();
  if (threadIdx.x == 0) {
    __hip_atomic_fetch_add(c, 1, __ATOMIC_ACQ_REL, __HIP_MEMORY_SCOPE_AGENT);
    while (__hip_atomic_load(c, __ATOMIC_ACQUIRE, __HIP_MEMORY_SCOPE_AGENT) < expected)
      __builtin_amdgcn_s_sleep(2);
  }
  __syncthreads();
}

// ---------- fused tail: convB(+fin1) -> [bar] -> stats2 -> [bar] -> stats3(+fin2) -> [bar] -> out(+fin3)
__global__ __launch_bounds__(256)
void tail_kernel(const float* __restrict__ gfp, const float* __restrict__ W1,
                 float* __restrict__ stats,
                 const float* __restrict__ g1, const float* __restrict__ b1,
                 const float* __restrict__ W2, float* __restrict__ u2t,
                 const float* __restrict__ W3,
                 const float* __restrict__ g2, const float* __restrict__ b2,
                 const float* __restrict__ g3, const float* __restrict__ b3,
                 float* __restrict__ out, int* __restrict__ bar) {
  const int tid = threadIdx.x;
  const int nthr = (int)gridDim.x * 256;          // 65536
  const int nblk = (int)gridDim.x;
  __shared__ float sA[64], sC[64];
  __shared__ float bs[128];

  // ---- phase0: convB (gf -> x1 -> conv2 -> lrelu -> u2t[col][64]) ----
  if (tid < 64) bn_coeff(stats, g1, b1, tid, sA[tid], sC[tid]);
  __syncthreads();
  for (int col = (int)blockIdx.x*256 + tid; col < BMK; col += nthr) {
    float gf[6];
#pragma unroll
    for (int c = 0; c < 6; ++c) gf[c] = gfp[c*BMK + col];
    float x1[64];
#pragma unroll
    for (int c = 0; c < 64; ++c) {
      float y = __fmul_rn(W1[c*6+0], gf[0]);
#pragma unroll
      for (int i = 1; i < 6; ++i) y = fmaf(W1[c*6+i], gf[i], y);
      float u = (y >= 0.f) ? y : 0.2f*y;
      x1[c] = fmaf(sA[c], u, sC[c]);
    }
    float* ob = u2t + (size_t)col * 64;
    for (int o4 = 0; o4 < 16; ++o4) {
      float y0 = 0.f, y1 = 0.f, y2 = 0.f, y3 = 0.f;
#pragma unroll
      for (int c = 0; c < 64; ++c) {
        float xc = x1[c];
        y0 = fmaf(W2[(o4*4+0)*64+c], xc, y0);
        y1 = fmaf(W2[(o4*4+1)*64+c], xc, y1);
        y2 = fmaf(W2[(o4*4+2)*64+c], xc, y2);
        y3 = fmaf(W2[(o4*4+3)*64+c], xc, y3);
      }
      float4 v;
      v.x = (y0 >= 0.f) ? y0 : 0.2f*y0;
      v.y = (y1 >= 0.f) ? y1 : 0.2f*y1;
      v.z = (y2 >= 0.f) ? y2 : 0.2f*y2;
      v.w = (y3 >= 0.f) ? y3 : 0.2f*y3;
      ((float4*)ob)[o4] = v;
    }
  }
  gridbar(&bar[0], nblk);

  // ---- phase1: stats2 (per-channel sum/sumsq of u2, coalesced float4) ----
  {
    const float4* u4 = (const float4*)u2t;
    const int nf4 = BMK * 16;
    float a0=0,a1=0,a2=0,a3=0,s0=0,s1=0,s2=0,s3=0;
    for (int i = (int)blockIdx.x*256 + tid; i < nf4; i += nthr) {
      float4 v = u4[i];
      a0 += v.x; s0 = fmaf(v.x, v.x, s0);
      a1 += v.y; s1 = fmaf(v.y, v.y, s1);
      a2 += v.z; s2 = fmaf(v.z, v.z, s2);
      a3 += v.w; s3 = fmaf(v.w, v.w, s3);
    }
    const int c0 = (4*tid) & 63;     // stride*4 ≡ 0 mod 64: channel fixed per thread
    if (tid < 128) bs[tid] = 0.f;
    __syncthreads();
    atomicAdd(&bs[c0+0], a0); atomicAdd(&bs[c0+1], a1);
    atomicAdd(&bs[c0+2], a2); atomicAdd(&bs[c0+3], a3);
    atomicAdd(&bs[64+c0+0], s0); atomicAdd(&bs[64+c0+1], s1);
    atomicAdd(&bs[64+c0+2], s2); atomicAdd(&bs[64+c0+3], s3);
    __syncthreads();
    if (tid < 128) atomicAdd(&stats[128 + tid], bs[tid]);
  }
  gridbar(&bar[1], nblk);

  // ---- phase2: stats3 (u3 = lrelu(W3f·u2 + b3f), per-channel sums) ----
  const int lane = tid & 63;
  float w[64];
  float bb = 0.f;
  {
    if (tid < 64) bn_coeff(stats + 128, g2, b2, tid, sA[tid], sC[tid]);
    __syncthreads();
#pragma unroll
    for (int c = 0; c < 64; ++c) w[c] = W3[lane*64 + c] * sA[c];   // == W3f
#pragma unroll
    for (int c = 0; c < 64; ++c) bb = fmaf(W3[lane*64 + c], sC[c], bb);  // == b3f
    const int gw = ((int)blockIdx.x*256 + tid) >> 6;
    const int nw = nthr >> 6;                 // 1024 waves
    float acc = 0.f, accq = 0.f;
    for (int col = gw; col < BMK; col += nw) {
      const float4* u4 = (const float4*)(u2t + (size_t)col*64);
      float y = bb;
#pragma unroll
      for (int c4 = 0; c4 < 16; ++c4) {
        float4 v = u4[c4];
        y = fmaf(w[4*c4+0], v.x, y);
        y = fmaf(w[4*c4+1], v.y, y);
        y = fmaf(w[4*c4+2], v.z, y);
        y = fmaf(w[4*c4+3], v.w, y);
      }
      float u = (y >= 0.f) ? y : 0.2f*y;
      acc += u; accq = fmaf(u, u, accq);
    }
    if (tid < 128) bs[tid] = 0.f;
    __syncthreads();
    atomicAdd(&bs[lane], acc);
    atomicAdd(&bs[64+lane], accq);
    __syncthreads();
    if (tid < 128) atomicAdd(&stats[256 + tid], bs[tid]);
  }
  gridbar(&bar[2], nblk);

  // ---- phase3: out (per (b,m) wave, recompute u3 over k, max, BN3) ----
  {
    float A3, C3;
    bn_coeff(stats + 256, g3, b3, lane, A3, C3);
    const int w0 = ((int)blockIdx.x*256 + tid) >> 6;
    const int nw = nthr >> 6;                 // 1024 waves
    for (int wv = w0; wv < B_*M_; wv += nw) {
      float mx = -3.4e38f, mn = 3.4e38f;
      for (int k = 0; k < K_; ++k) {
        const float4* u4 = (const float4*)(u2t + ((size_t)wv*K_ + k)*64);
        float y = bb;
#pragma unroll
        for (int c4 = 0; c4 < 16; ++c4) {
          float4 v = u4[c4];
          y = fmaf(w[4*c4+0], v.x, y);
          y = fmaf(w[4*c4+1], v.y, y);
          y = fmaf(w[4*c4+2], v.z, y);
          y = fmaf(w[4*c4+3], v.w, y);
        }
        float u = (y >= 0.f) ? y : 0.2f*y;
        mx = fmaxf(mx, u); mn = fminf(mn, u);
      }
      float r = (A3 >= 0.f) ? mx : mn;   // affine commutes with max when a>=0
      int b = wv >> 11, m = wv & 2047;
      out[((size_t)(b*64 + lane))*M_ + m] = fmaf(A3, r, C3);
    }
  }
}

// ---------- launch ----------
extern "C" void kernel_launch(void* const* d_in, const int* in_sizes, int n_in,
                              void* d_out, int out_size, void* d_ws, size_t ws_size,
                              hipStream_t stream) {
  const float* p  = (const float*)d_in[0];
  const float* W1 = (const float*)d_in[1];
  const float* g1 = (const float*)d_in[2];
  const float* b1 = (const float*)d_in[3];
  const float* W2 = (const float*)d_in[4];
  const float* g2 = (const float*)d_in[5];
  const float* b2 = (const float*)d_in[6];
  const float* W3 = (const float*)d_in[7];
  const float* g3 = (const float*)d_in[8];
  const float* b3 = (const float*)d_in[9];
  float* out = (float*)d_out;
  char* ws = (char*)d_ws;

  // workspace layout (~46.2 MB total)
  float* p1    = (float*)(ws);                 // 98,304 B
  float* gfp   = (float*)(ws + 131072);        // 3,932,160 B
  float* u2t   = (float*)(ws + 4194304);       // 41,943,040 B
  float* stats = (float*)(ws + 46137344);      // 384 f (sum/sq x3 layers)
  int*   prog  = (int*)(ws + 46138880);        // 4 ints: fps progress per batch
  int*   bar   = (int*)(ws + 46138896);        // 3 ints: grid barrier counters

  hipMemsetAsync((void*)stats, 0, 1568, stream);   // stats + prog + bar
  hipLaunchKernelGGL(fpsknn_kernel, dim3(B_ + PERS), dim3(512), 0, stream,
                     p, p1, gfp, W1, stats, prog);
  hipLaunchKernelGGL(tail_kernel,   dim3(256), dim3(256), 0, stream,
                     gfp, W1, stats, g1, b1, W2, u2t, W3, g2, b2, g3, b3, out, bar);
}

// Round 7
// 2392.872 us; speedup vs baseline: 1.0507x; 1.0507x over previous
//
#include <hip/hip_runtime.h>
#include <cstdint>
#include <cstddef>

// GroupPointNet: FPS -> kNN(20) -> gf=(dp,grouped) -> 3x(conv1x1+lrelu+BN) -> max_k
// B=4, N=8192, M=2048, K=20, C=64. All f32.
// R13: fpsknn (R11, unchanged). Tail rebuilt: 3 phases / 2 grid barriers.
//   Phase A: convB with lane=channel + W2 row in 64 VGPRs (kills the 2.6GB scalar-cache
//            W2 re-fetch) + stats2 fused in-pass (kills a 42MB re-read).
//   Phase B: stats3 + per-(b,m) min/max stash (kills out's 42MB recompute pass).
//   Phase C: tiny BN3 finalize from the 4MB stash (overlaid on dead p1/gfp region).

#define B_ 4
#define N_ 8192
#define M_ 2048
#define K_ 20
#define BMK (B_*M_*K_)   // 163840
#define EPS_ 1e-5f
#define TILE_ 1024
#define PERS 248

typedef unsigned long long ull;
typedef float f32x2 __attribute__((ext_vector_type(2)));

// ---------- helpers ----------
__device__ __forceinline__ ull packkey(float d, int idx) {
  unsigned int bb = __float_as_uint(d);
  bb ^= (bb & 0x80000000u) ? 0xFFFFFFFFu : 0x80000000u;  // order-preserving map
  return ((ull)bb << 32) | (unsigned int)idx;
}
__device__ __forceinline__ float keymaxf(ull k) {
  unsigned int hb = (unsigned int)(k >> 32);
  unsigned int fb = (hb & 0x80000000u) ? (hb ^ 0x80000000u) : ~hb;
  return __uint_as_float(fb);
}
// keys sorted ascending; caller guarantees key < keys[19]
__device__ __forceinline__ void insert20(ull* keys, ull key) {
#pragma unroll
  for (int i = 19; i > 0; --i) {
    ull lo = keys[i-1];
    keys[i] = (key < lo) ? lo : ((key < keys[i]) ? key : keys[i]);
  }
  keys[0] = (key < keys[0]) ? key : keys[0];
}

#define DPPMAXU(V, CTRL) {                                                           \
    unsigned int nh = (unsigned int)__builtin_amdgcn_update_dpp(                     \
        (int)V, (int)V, CTRL, 0xF, 0xF, false);                                      \
    V = (nh > V) ? nh : V; }

// ---------- fused fps + knn + stats1 (R11, unchanged) ----------
__global__ __launch_bounds__(512)
void fpsknn_kernel(const float* __restrict__ p, float* __restrict__ p1,
                   float* __restrict__ gfp, const float* __restrict__ W1,
                   float* __restrict__ stats, int* __restrict__ prog) {
  __shared__ union {
    struct { float4 pts4[N_]; unsigned int slotsv[2][8]; int idxsel[2]; } f;  // 131144 B
    struct { float4 tile[TILE_]; ull mk[8*32*20]; float bs[128]; } k;         // 57856 B
  } sm;
  const int tid = threadIdx.x;

  if (blockIdx.x < B_) {
    // ================= FPS role (R7 verbatim) ==========
#pragma clang fp contract(off)
    const int b = blockIdx.x;
    const float* pb = p + (size_t)b * (N_*3);
    float* p1b = p1 + (size_t)b * (M_*3);
    float4* pts4 = sm.f.pts4;
    const int wv = tid >> 6;                   // wave 0..7
    const int base = tid * 16;                 // 16 points per thread, 8 float2 pairs
    f32x2 X[8], Y[8], Z[8], D[8];
#pragma unroll
    for (int j = 0; j < 8; ++j) {
      int i = base + 2*j;
      float x0 = pb[i*3+0], y0 = pb[i*3+1], z0 = pb[i*3+2];
      float x1 = pb[i*3+3], y1 = pb[i*3+4], z1 = pb[i*3+5];
      X[j] = (f32x2){x0, x1};
      Y[j] = (f32x2){y0, y1};
      Z[j] = (f32x2){z0, z1};
      D[j] = (f32x2){1e10f, 1e10f};
      pts4[i]   = make_float4(x0, y0, z0, 0.f);
      pts4[i+1] = make_float4(x1, y1, z1, 0.f);
    }
    if (tid < 2) sm.f.idxsel[tid] = 0x7FFFFFFF;
    float qx = pb[0], qy = pb[1], qz = pb[2];  // idx0 = 0
    if (tid == 0) { p1b[0] = qx; p1b[1] = qy; p1b[2] = qz; }
    __syncthreads();
    for (int t = 1; t < M_; ++t) {
      const int cur = t & 1;
      f32x2 q2x = (f32x2){qx, qx};
      f32x2 q2y = (f32x2){qy, qy};
      f32x2 q2z = (f32x2){qz, qz};
      f32x2 tmx = (f32x2){-1.f, -1.f};
#pragma unroll
      for (int j = 0; j < 8; ++j) {
        // plain vector ops (contract off): per-lane rounding identical to XLA
        f32x2 dx = X[j] - q2x;
        f32x2 dy = Y[j] - q2y;
        f32x2 dz = Z[j] - q2z;
        f32x2 s = (dx*dx + dy*dy) + dz*dz;
        f32x2 dj = __builtin_elementwise_min(D[j], s);
        D[j] = dj;
        tmx = __builtin_elementwise_max(tmx, dj);
      }
      float tm = fmaxf(tmx.x, tmx.y);
      const unsigned int tmb = __float_as_uint(tm);  // d>=0: bit order == float order
      unsigned int hv = tmb;
      DPPMAXU(hv, 0x111)  // row_shr:1
      DPPMAXU(hv, 0x112)  // row_shr:2
      DPPMAXU(hv, 0x114)  // row_shr:4
      DPPMAXU(hv, 0x118)  // row_shr:8
      DPPMAXU(hv, 0x142)  // row_bcast:15
      DPPMAXU(hv, 0x143)  // row_bcast:31
      if ((tid & 63) == 63) sm.f.slotsv[cur][wv] = hv;
      __syncthreads();                         // barrier 1: slots ready
      if (tid == 0) sm.f.idxsel[cur ^ 1] = 0x7FFFFFFF;   // prep slot for t+1
      unsigned int g = sm.f.slotsv[cur][0];
#pragma unroll
      for (int j = 1; j < 8; ++j) { unsigned int s2 = sm.f.slotsv[cur][j]; g = (s2 > g) ? s2 : g; }
      if (tmb == g) {                          // holder(s) of the max
        int fj = 0x7FFFFFFF;
#pragma unroll
        for (int j = 7; j >= 0; --j) {         // descending so lowest index wins
          if (__float_as_uint(D[j].y) == g) fj = base + 2*j + 1;
          if (__float_as_uint(D[j].x) == g) fj = base + 2*j;
        }
        atomicMin(&sm.f.idxsel[cur], fj);      // global first-index tie-break
      }
      __syncthreads();                         // barrier 2: index final
      int sel = sm.f.idxsel[cur];
      sel = __builtin_amdgcn_readfirstlane(sel);
      float4 qv = pts4[sel];                   // broadcast ds_read_b128
      qx = qv.x; qy = qv.y; qz = qv.z;
      if (tid == 0) {
        p1b[t*3+0] = qx; p1b[t*3+1] = qy; p1b[t*3+2] = qz;
        if ((t & 63) == 63)
          __hip_atomic_store(&prog[b], t, __ATOMIC_RELEASE, __HIP_MEMORY_SCOPE_AGENT);
      }
    }
    if (tid == 0)
      __hip_atomic_store(&prog[b], M_, __ATOMIC_RELEASE, __HIP_MEMORY_SCOPE_AGENT);
    return;
  }

  // ================= kNN + stats1 role (persistent consumer) ======================
  float4* tile = sm.k.tile;
  ull* mk = sm.k.mk;
  float* gfl = (float*)sm.k.tile;              // overlays tile after the scan phase
  float* bs = sm.k.bs;
  for (int ord = (int)blockIdx.x - B_; ord < 1024; ord += PERS) {
    const int b = ord & 3;                     // readiness-ordered chunks per block
    const int q0 = (ord >> 2) * 8;
    if (tid == 0) {
      while (__hip_atomic_load(&prog[b], __ATOMIC_ACQUIRE, __HIP_MEMORY_SCOPE_AGENT) < q0 + 7)
        __builtin_amdgcn_s_sleep(16);
    }
    __syncthreads();
    { int pv = __hip_atomic_load(&prog[b], __ATOMIC_ACQUIRE, __HIP_MEMORY_SCOPE_AGENT);
      asm volatile("" :: "v"(pv)); }           // per-thread acquire, kept live

    const int ql = (tid >> 5) & 7;             // query within block (tid<256 active)
    const int part = tid & 31;
    const int m = q0 + ql;
    const float* pb = p + (size_t)b*(N_*3);
    const float* qp_ = p1 + ((size_t)b*M_ + m)*3;
    float qx = qp_[0], qy = qp_[1], qz = qp_[2];
    float qq = __fadd_rn(__fadd_rn(__fmul_rn(qx,qx), __fmul_rn(qy,qy)), __fmul_rn(qz,qz));
    ull keys[20];
#pragma unroll
    for (int i = 0; i < 20; ++i) keys[i] = 0xFF8000007FFFFFFFull;  // pack(+inf, INT_MAX)
    float maxf = __uint_as_float(0x7F800000u);  // +inf
    for (int t0 = 0; t0 < N_; t0 += TILE_) {
      __syncthreads();                          // also guards gfl/tile reuse across chunks
      for (int i = tid; i < TILE_; i += 512) {
        float x = pb[(t0+i)*3+0], y = pb[(t0+i)*3+1], z = pb[(t0+i)*3+2];
        float pp = __fadd_rn(__fadd_rn(__fmul_rn(x,x), __fmul_rn(y,y)), __fmul_rn(z,z));
        tile[i] = make_float4(x, y, z, pp);
      }
      __syncthreads();
      if (tid < 256) {
        const int sbase = part * 32;
        for (int s = 0; s < 32; ++s) {
          int ss = sbase + ((s + part) & 31);   // bank skew across parts
          float4 pt = tile[ss];
          float qp = fmaf(pt.z, qz, fmaf(pt.y, qy, __fmul_rn(pt.x, qx)));
          float d = __fsub_rn(__fadd_rn(qq, pt.w), __fmul_rn(2.0f, qp));
          if (d <= maxf) {
            ull key = packkey(d, t0 + ss);
            if (key < keys[19]) { insert20(keys, key); maxf = keymaxf(keys[19]); }
          }
        }
      }
    }
    if (tid < 256) {
      ull* myslot = &mk[(ql*32 + part)*20];
#pragma unroll
      for (int i = 0; i < 20; ++i) myslot[i] = keys[i];
    }
    __syncthreads();
    if (tid < 256 && part == 0) {   // leader merges 32x20 sorted lists
      for (int pp2 = 1; pp2 < 32; ++pp2) {
        const ull* os = &mk[(ql*32 + pp2)*20];
        for (int i = 0; i < 20; ++i) {
          ull k = os[i];
          if (k >= keys[19]) break;    // sorted -> rest can't enter
          insert20(keys, k);
        }
      }
      ull* myslot = &mk[(ql*32)*20];
#pragma unroll
      for (int i = 0; i < 20; ++i) myslot[i] = keys[i];
    }
    __syncthreads();
    // gf write (global planes) + LDS stash for the stats1 tail
    for (int w = tid; w < 8*K_; w += 512) {
      int ql2 = w / K_;
      int kk = w - ql2*K_;
      ull key = mk[ql2*32*20 + kk];
      int idx = (int)(unsigned int)(key & 0xFFFFFFFFu);
      float gx = pb[idx*3+0], gy = pb[idx*3+1], gz = pb[idx*3+2];
      int m2 = q0 + ql2;
      const float* qv = p1 + ((size_t)b*M_ + m2)*3;
      size_t col = ((size_t)(b*M_ + m2))*K_ + kk;
      float d0 = __fsub_rn(gx, qv[0]);
      float d1 = __fsub_rn(gy, qv[1]);
      float d2 = __fsub_rn(gz, qv[2]);
      gfp[0*BMK + col] = d0;
      gfp[1*BMK + col] = d1;
      gfp[2*BMK + col] = d2;
      gfp[3*BMK + col] = gx;
      gfp[4*BMK + col] = gy;
      gfp[5*BMK + col] = gz;
      gfl[w*6+0] = d0; gfl[w*6+1] = d1; gfl[w*6+2] = d2;
      gfl[w*6+3] = gx; gfl[w*6+4] = gy; gfl[w*6+5] = gz;
    }
    __syncthreads();
    // stats1 tail: 8 grps x 64 lanes(=channels), 20 cols each (same fmaf sequence)
    {
      const int lane = tid & 63;
      const int grp = tid >> 6;
      float w1r[6];
#pragma unroll
      for (int c = 0; c < 6; ++c) w1r[c] = W1[lane*6 + c];
      float acc = 0.f, accq = 0.f;
      for (int cc = 0; cc < 20; ++cc) {
        const float* gv = &gfl[(grp*20 + cc)*6];
        float y = __fmul_rn(w1r[0], gv[0]);
#pragma unroll
        for (int c = 1; c < 6; ++c) y = fmaf(w1r[c], gv[c], y);
        float u = (y >= 0.f) ? y : 0.2f*y;
        acc += u;
        accq = fmaf(u, u, accq);
      }
      if (tid < 128) bs[tid] = 0.f;
      __syncthreads();
      atomicAdd(&bs[lane], acc);
      atomicAdd(&bs[64+lane], accq);
      __syncthreads();
      if (tid < 128) atomicAdd(&stats[tid], bs[tid]);
    }
  }
}

// BN coefficient replication (bit-identical to the old finalize_kernel)
__device__ __forceinline__ void bn_coeff(const float* __restrict__ st,
                                         const float* __restrict__ g,
                                         const float* __restrict__ bb,
                                         int o, float& A, float& C) {
  const float inv = 1.0f / (float)BMK;
  float mean = st[o] * inv;
  float var  = st[64+o] * inv - mean*mean;
  float a = g[o] / sqrtf(var + EPS_);
  A = a;
  C = fmaf(-a, mean, bb[o]);
}

// software grid barrier: all blocks co-resident (512 blocks x 4 waves << capacity)
__device__ __forceinline__ void gridbar(int* c, int expected) {
  __syncthreads();
  if (threadIdx.x == 0) {
    __hip_atomic_fetch_add(c, 1, __ATOMIC_ACQ_REL, __HIP_MEMORY_SCOPE_AGENT);
    while (__hip_atomic_load(c, __ATOMIC_ACQUIRE, __HIP_MEMORY_SCOPE_AGENT) < expected)
      __builtin_amdgcn_s_sleep(2);
  }
  __syncthreads();
}

// ---------- fused tail v2 ----------
// A: convB+stats2 (lane=channel, W2 row in VGPRs, x1 bcast via per-wave LDS slice)
// B: stats3 + per-(b,m) min/max stash (pmx/pmn overlay dead p1/gfp region)
// C: BN3 finalize from stash.
__global__ __launch_bounds__(256)
void tail_kernel(const float* __restrict__ gfp, const float* __restrict__ W1,
                 float* __restrict__ stats,
                 const float* __restrict__ g1, const float* __restrict__ b1,
                 const float* __restrict__ W2, float* __restrict__ u2t,
                 const float* __restrict__ W3,
                 const float* __restrict__ g2, const float* __restrict__ b2,
                 const float* __restrict__ g3, const float* __restrict__ b3,
                 float* __restrict__ out, int* __restrict__ bar,
                 float* __restrict__ pmx, float* __restrict__ pmn) {
  const int tid = threadIdx.x;
  const int nblk = (int)gridDim.x;
  const int lane = tid & 63;
  const int wid = ((int)blockIdx.x*256 + tid) >> 6;   // global wave id
  const int nw = (nblk*256) >> 6;                      // total waves (2048)
  __shared__ float sA[64], sC[64];
  __shared__ float bs[128];
  __shared__ float xbuf[4][64];                        // per-wave x1 broadcast slice
  float* xb = xbuf[(tid >> 6) & 3];

  // ---- phase A: convB (lane=channel) + fused stats2 ----
  {
    if (tid < 64) bn_coeff(stats, g1, b1, tid, sA[tid], sC[tid]);
    __syncthreads();
    float w1r[6];
#pragma unroll
    for (int c = 0; c < 6; ++c) w1r[c] = W1[lane*6 + c];
    const float sAl = sA[lane], sCl = sC[lane];
    float wrow[64];
#pragma unroll
    for (int c = 0; c < 64; ++c) wrow[c] = W2[lane*64 + c];
    float acc = 0.f, accq = 0.f;
    float gfn[6];
    int col = wid;
    if (col < BMK) {
#pragma unroll
      for (int c = 0; c < 6; ++c) gfn[c] = gfp[c*BMK + col];
    }
    for (; col < BMK; col += nw) {
      float gfc[6];
#pragma unroll
      for (int c = 0; c < 6; ++c) gfc[c] = gfn[c];
      if (col + nw < BMK) {                  // prefetch next col's gf
#pragma unroll
        for (int c = 0; c < 6; ++c) gfn[c] = gfp[c*BMK + (col + nw)];
      }
      // x1 for channel = lane (same fmaf sequence as original convB)
      float y = __fmul_rn(w1r[0], gfc[0]);
#pragma unroll
      for (int c = 1; c < 6; ++c) y = fmaf(w1r[c], gfc[c], y);
      float u = (y >= 0.f) ? y : 0.2f*y;
      float x1v = fmaf(sAl, u, sCl);
      xb[lane] = x1v;                        // intra-wave broadcast (lgkmcnt-ordered)
      float yo = 0.f;
      const float4* xb4 = (const float4*)xb;
#pragma unroll
      for (int c4 = 0; c4 < 16; ++c4) {      // c ascending 0..63, same order as before
        float4 v = xb4[c4];
        yo = fmaf(wrow[4*c4+0], v.x, yo);
        yo = fmaf(wrow[4*c4+1], v.y, yo);
        yo = fmaf(wrow[4*c4+2], v.z, yo);
        yo = fmaf(wrow[4*c4+3], v.w, yo);
      }
      float u2 = (yo >= 0.f) ? yo : 0.2f*yo;
      u2t[(size_t)col*64 + lane] = u2;       // coalesced 256B per wave
      acc += u2;
      accq = fmaf(u2, u2, accq);
    }
    if (tid < 128) bs[tid] = 0.f;
    __syncthreads();
    atomicAdd(&bs[lane], acc);
    atomicAdd(&bs[64+lane], accq);
    __syncthreads();
    if (tid < 128) atomicAdd(&stats[128 + tid], bs[tid]);
  }
  gridbar(&bar[0], nblk);

  // ---- phase B: stats3 sums + per-(b,m) min/max stash ----
  float w3[64];
  float bb = 0.f;
  {
    if (tid < 64) bn_coeff(stats + 128, g2, b2, tid, sA[tid], sC[tid]);
    __syncthreads();
#pragma unroll
    for (int c = 0; c < 64; ++c) w3[c] = W3[lane*64 + c] * sA[c];   // == W3f
#pragma unroll
    for (int c = 0; c < 64; ++c) bb = fmaf(W3[lane*64 + c], sC[c], bb);  // == b3f
    float acc = 0.f, accq = 0.f;
    for (int wv = wid; wv < B_*M_; wv += nw) {
      float mx = -3.4e38f, mn = 3.4e38f;
      for (int k = 0; k < K_; ++k) {
        const float4* u4 = (const float4*)(u2t + ((size_t)wv*K_ + k)*64);
        float y = bb;
#pragma unroll
        for (int c4 = 0; c4 < 16; ++c4) {
          float4 v = u4[c4];
          y = fmaf(w3[4*c4+0], v.x, y);
          y = fmaf(w3[4*c4+1], v.y, y);
          y = fmaf(w3[4*c4+2], v.z, y);
          y = fmaf(w3[4*c4+3], v.w, y);
        }
        float u = (y >= 0.f) ? y : 0.2f*y;
        acc += u; accq = fmaf(u, u, accq);
        mx = fmaxf(mx, u); mn = fminf(mn, u);
      }
      pmx[(size_t)wv*64 + lane] = mx;        // coalesced
      pmn[(size_t)wv*64 + lane] = mn;
    }
    if (tid < 128) bs[tid] = 0.f;
    __syncthreads();
    atomicAdd(&bs[lane], acc);
    atomicAdd(&bs[64+lane], accq);
    __syncthreads();
    if (tid < 128) atomicAdd(&stats[256 + tid], bs[tid]);
  }
  gridbar(&bar[1], nblk);

  // ---- phase C: BN3 finalize from stash ----
  {
    float A3, C3;
    bn_coeff(stats + 256, g3, b3, lane, A3, C3);
    for (int wv = wid; wv < B_*M_; wv += nw) {
      float mx = pmx[(size_t)wv*64 + lane];
      float mn = pmn[(size_t)wv*64 + lane];
      float r = (A3 >= 0.f) ? mx : mn;       // affine commutes with max when a>=0
      int b = wv >> 11, m = wv & 2047;
      out[((size_t)(b*64 + lane))*M_ + m] = fmaf(A3, r, C3);
    }
  }
}

// ---------- launch ----------
extern "C" void kernel_launch(void* const* d_in, const int* in_sizes, int n_in,
                              void* d_out, int out_size, void* d_ws, size_t ws_size,
                              hipStream_t stream) {
  const float* p  = (const float*)d_in[0];
  const float* W1 = (const float*)d_in[1];
  const float* g1 = (const float*)d_in[2];
  const float* b1 = (const float*)d_in[3];
  const float* W2 = (const float*)d_in[4];
  const float* g2 = (const float*)d_in[5];
  const float* b2 = (const float*)d_in[6];
  const float* W3 = (const float*)d_in[7];
  const float* g3 = (const float*)d_in[8];
  const float* b3 = (const float*)d_in[9];
  float* out = (float*)d_out;
  char* ws = (char*)d_ws;

  // workspace layout (~46.2 MB total)
  float* p1    = (float*)(ws);                 // 98,304 B   (dead after fpsknn)
  float* gfp   = (float*)(ws + 131072);        // 3,932,160 B (dead after tail phase A)
  float* u2t   = (float*)(ws + 4194304);       // 41,943,040 B
  float* stats = (float*)(ws + 46137344);      // 384 f (sum/sq x3 layers)
  int*   prog  = (int*)(ws + 46138880);        // 4 ints: fps progress per batch
  int*   bar   = (int*)(ws + 46138896);        // 3 ints: grid barrier counters
  // min/max stash (phase B->C) overlays the dead p1+gfp region: 2x 2MB within [0, 4MB)
  float* pmx   = (float*)(ws);                 // 2,097,152 B
  float* pmn   = (float*)(ws + 2097152);       // 2,097,152 B

  hipMemsetAsync((void*)stats, 0, 1568, stream);   // stats + prog + bar
  hipLaunchKernelGGL(fpsknn_kernel, dim3(B_ + PERS), dim3(512), 0, stream,
                     p, p1, gfp, W1, stats, prog);
  hipLaunchKernelGGL(tail_kernel,   dim3(512), dim3(256), 0, stream,
                     gfp, W1, stats, g1, b1, W2, u2t, W3, g2, b2, g3, b3, out, bar,
                     pmx, pmn);
}

// Round 9
// 2280.585 us; speedup vs baseline: 1.1024x; 1.0492x over previous
//
#include <hip/hip_runtime.h>
#include <cstdint>
#include <cstddef>

// GroupPointNet: FPS -> kNN(20) -> gf=(dp,grouped) -> 3x(conv1x1+lrelu+BN) -> max_k
// B=4, N=8192, M=2048, K=20, C=64. All f32.
// R15: R14 resubmit (round-8 bench died on container infra, no kernel signal).
//      Bucket-pruned FPS (exactness-preserving). Prologue: bbox -> Morton cell keys ->
//      LDS counting sort; each thread owns 16 sorted points + AABB + orig idx.
//      Main loop: skip bucket iff lb(AABB,q)^2 > cached bucket max d  (IEEE-monotone
//      lower bound with identical op association => skipped fmins are provable no-ops;
//      results bit-identical). Reduce/tie-break: value DPP on bucket max + atomicMin of
//      packed (origidx<<13|spos). Consumers + tail (R13) unchanged.

#define B_ 4
#define N_ 8192
#define M_ 2048
#define K_ 20
#define BMK (B_*M_*K_)   // 163840
#define EPS_ 1e-5f
#define TILE_ 1024
#define PERS 248

typedef unsigned long long ull;
typedef float f32x2 __attribute__((ext_vector_type(2)));

// ---------- helpers ----------
__device__ __forceinline__ ull packkey(float d, int idx) {
  unsigned int bb = __float_as_uint(d);
  bb ^= (bb & 0x80000000u) ? 0xFFFFFFFFu : 0x80000000u;  // order-preserving map
  return ((ull)bb << 32) | (unsigned int)idx;
}
__device__ __forceinline__ float keymaxf(ull k) {
  unsigned int hb = (unsigned int)(k >> 32);
  unsigned int fb = (hb & 0x80000000u) ? (hb ^ 0x80000000u) : ~hb;
  return __uint_as_float(fb);
}
// keys sorted ascending; caller guarantees key < keys[19]
__device__ __forceinline__ void insert20(ull* keys, ull key) {
#pragma unroll
  for (int i = 19; i > 0; --i) {
    ull lo = keys[i-1];
    keys[i] = (key < lo) ? lo : ((key < keys[i]) ? key : keys[i]);
  }
  keys[0] = (key < keys[0]) ? key : keys[0];
}

__device__ __forceinline__ unsigned int mapmono(float f) {   // order-preserving f32->u32
  unsigned int u = __float_as_uint(f);
  return u ^ ((u & 0x80000000u) ? 0xFFFFFFFFu : 0x80000000u);
}
__device__ __forceinline__ float unmapmono(unsigned int u) {
  unsigned int f = (u & 0x80000000u) ? (u ^ 0x80000000u) : ~u;
  return __uint_as_float(f);
}
__device__ __forceinline__ int mspread(int v) {  // 3-bit spread for Morton
  return (v & 1) | ((v & 2) << 2) | ((v & 4) << 4);
}

#define DPPMAXU(V, CTRL) {                                                           \
    unsigned int nh = (unsigned int)__builtin_amdgcn_update_dpp(                     \
        (int)V, (int)V, CTRL, 0xF, 0xF, false);                                      \
    V = (nh > V) ? nh : V; }

// ---------- fused fps + knn + stats1 ----------
__global__ __launch_bounds__(512)
void fpsknn_kernel(const float* __restrict__ p, float* __restrict__ p1,
                   float* __restrict__ gfp, const float* __restrict__ W1,
                   float* __restrict__ stats, int* __restrict__ prog) {
  __shared__ union {
    struct { float4 pts4[N_]; unsigned int slotsv[2][8]; int idxsel[2];
             unsigned int hist[520]; } f;                                     // ~133 KB
    struct { float4 tile[TILE_]; ull mk[8*32*20]; float bs[128]; } k;         // 57856 B
  } sm;
  const int tid = threadIdx.x;

  if (blockIdx.x < B_) {
    // ================= FPS role: bucket-pruned, bit-exact ==========
#pragma clang fp contract(off)
    const int b = blockIdx.x;
    const float* pb = p + (size_t)b * (N_*3);
    float* p1b = p1 + (size_t)b * (M_*3);
    float4* pts4 = sm.f.pts4;
    unsigned int* hist = sm.f.hist;
    const int wv = tid >> 6;                   // wave 0..7
    const int base = tid * 16;

    // ---- prologue 1: load 16 orig points to temp regs ----
    float tx[16], ty[16], tz[16];
#pragma unroll
    for (int j = 0; j < 16; ++j) {
      int i = base + j;
      tx[j] = pb[i*3+0]; ty[j] = pb[i*3+1]; tz[j] = pb[i*3+2];
    }
    for (int i = tid; i < 520; i += 512) hist[i] = 0;
    __syncthreads();
    // ---- prologue 2: bbox via LDS atomicMax on monotone-mapped u32 ----
    {
      unsigned int axp = 0, axn = 0, ayp = 0, ayn = 0, azp = 0, azn = 0;
#pragma unroll
      for (int j = 0; j < 16; ++j) {
        axp = max(axp, mapmono(tx[j])); axn = max(axn, mapmono(-tx[j]));
        ayp = max(ayp, mapmono(ty[j])); ayn = max(ayn, mapmono(-ty[j]));
        azp = max(azp, mapmono(tz[j])); azn = max(azn, mapmono(-tz[j]));
      }
      atomicMax(&hist[512], axp); atomicMax(&hist[513], axn);
      atomicMax(&hist[514], ayp); atomicMax(&hist[515], ayn);
      atomicMax(&hist[516], azp); atomicMax(&hist[517], azn);
    }
    __syncthreads();
    const float bminx = -unmapmono(hist[513]), bmaxx = unmapmono(hist[512]);
    const float bminy = -unmapmono(hist[515]), bmaxy = unmapmono(hist[514]);
    const float bminz = -unmapmono(hist[517]), bmaxz = unmapmono(hist[516]);
    const float wx_ = bmaxx - bminx, wy_ = bmaxy - bminy, wz_ = bmaxz - bminz;
    const float ivx = (wx_ > 0.f) ? 8.0f/wx_ : 0.f;
    const float ivy = (wy_ > 0.f) ? 8.0f/wy_ : 0.f;
    const float ivz = (wz_ > 0.f) ? 8.0f/wz_ : 0.f;
    __syncthreads();
    // ---- prologue 3: histogram of Morton cells ----
#pragma unroll
    for (int j = 0; j < 16; ++j) {
      int kx = min((int)((tx[j]-bminx)*ivx), 7);
      int ky = min((int)((ty[j]-bminy)*ivy), 7);
      int kz = min((int)((tz[j]-bminz)*ivz), 7);
      int cell = mspread(kx) | (mspread(ky) << 1) | (mspread(kz) << 2);
      atomicAdd(&hist[cell], 1u);
    }
    __syncthreads();
    // ---- prologue 4: Hillis-Steele inclusive scan -> exclusive offsets ----
    {
      unsigned int cnt = hist[tid];
      unsigned int v = cnt;
      for (int s = 1; s < 512; s <<= 1) {
        unsigned int t2 = (tid >= s) ? hist[tid - s] : 0u;
        __syncthreads();
        v += t2;
        hist[tid] = v;
        __syncthreads();
      }
      hist[tid] = v - cnt;                     // exclusive
    }
    __syncthreads();
    // ---- prologue 5: scatter into sorted pts4 (.w = orig idx bits) ----
#pragma unroll
    for (int j = 0; j < 16; ++j) {
      int kx = min((int)((tx[j]-bminx)*ivx), 7);
      int ky = min((int)((ty[j]-bminy)*ivy), 7);
      int kz = min((int)((tz[j]-bminz)*ivz), 7);
      int cell = mspread(kx) | (mspread(ky) << 1) | (mspread(kz) << 2);
      unsigned int pos = atomicAdd(&hist[cell], 1u);
      pts4[pos] = make_float4(tx[j], ty[j], tz[j], __int_as_float(base + j));
    }
    __syncthreads();
    // ---- prologue 6: reload sorted bucket (16 pts) + AABB + orig idx ----
    f32x2 X[8], Y[8], Z[8], D[8];
    int oidx[16];
    float bxmn = 3.4e38f, bxmx = -3.4e38f, bymn = 3.4e38f, bymx = -3.4e38f;
    float bzmn = 3.4e38f, bzmx = -3.4e38f;
#pragma unroll
    for (int j = 0; j < 8; ++j) {
      float4 a = pts4[base + 2*j];
      float4 c = pts4[base + 2*j + 1];
      X[j] = (f32x2){a.x, c.x};
      Y[j] = (f32x2){a.y, c.y};
      Z[j] = (f32x2){a.z, c.z};
      D[j] = (f32x2){1e10f, 1e10f};
      oidx[2*j]   = __float_as_int(a.w);
      oidx[2*j+1] = __float_as_int(c.w);
      bxmn = fminf(bxmn, fminf(a.x, c.x)); bxmx = fmaxf(bxmx, fmaxf(a.x, c.x));
      bymn = fminf(bymn, fminf(a.y, c.y)); bymx = fmaxf(bymx, fmaxf(a.y, c.y));
      bzmn = fminf(bzmn, fminf(a.z, c.z)); bzmx = fmaxf(bzmx, fmaxf(a.z, c.z));
    }
    float cmax = 1e10f;                        // bucket max d (exact at all times)
    if (tid < 2) sm.f.idxsel[tid] = 0x7FFFFFFF;
    float qx = pb[0], qy = pb[1], qz = pb[2];  // idx0 = 0
    if (tid == 0) { p1b[0] = qx; p1b[1] = qy; p1b[2] = qz; }
    __syncthreads();

    for (int t = 1; t < M_; ++t) {
      const int cur = t & 1;
      // AABB lower bound, same op-association as per-point s => s_lb <= s (monotone fl)
      float dxl = fmaxf(fmaxf(bxmn - qx, qx - bxmx), 0.f);
      float dyl = fmaxf(fmaxf(bymn - qy, qy - bymx), 0.f);
      float dzl = fmaxf(fmaxf(bzmn - qz, qz - bzmx), 0.f);
      float slb = (dxl*dxl + dyl*dyl) + dzl*dzl;
      if (slb <= cmax) {                       // must scan (else provable no-op)
        f32x2 q2x = (f32x2){qx, qx};
        f32x2 q2y = (f32x2){qy, qy};
        f32x2 q2z = (f32x2){qz, qz};
        f32x2 tmx = (f32x2){-1.f, -1.f};
#pragma unroll
        for (int j = 0; j < 8; ++j) {
          f32x2 dx = X[j] - q2x;
          f32x2 dy = Y[j] - q2y;
          f32x2 dz = Z[j] - q2z;
          f32x2 s = (dx*dx + dy*dy) + dz*dz;
          f32x2 dj = __builtin_elementwise_min(D[j], s);
          D[j] = dj;
          tmx = __builtin_elementwise_max(tmx, dj);
        }
        cmax = fmaxf(tmx.x, tmx.y);
      }
      const unsigned int tmb = __float_as_uint(cmax);  // d>=0: bit order == float order
      unsigned int hv = tmb;
      DPPMAXU(hv, 0x111)  // row_shr:1
      DPPMAXU(hv, 0x112)  // row_shr:2
      DPPMAXU(hv, 0x114)  // row_shr:4
      DPPMAXU(hv, 0x118)  // row_shr:8
      DPPMAXU(hv, 0x142)  // row_bcast:15
      DPPMAXU(hv, 0x143)  // row_bcast:31
      if ((tid & 63) == 63) sm.f.slotsv[cur][wv] = hv;
      __syncthreads();                         // barrier 1: slots ready
      if (tid == 0) sm.f.idxsel[cur ^ 1] = 0x7FFFFFFF;   // prep slot for t+1
      unsigned int g = sm.f.slotsv[cur][0];
#pragma unroll
      for (int j = 1; j < 8; ++j) { unsigned int s2 = sm.f.slotsv[cur][j]; g = (s2 > g) ? s2 : g; }
      if (tmb == g) {                          // bucket(s) holding the global max
        int best = 0x7FFFFFFF;                 // packed (origidx<<13)|spos: min == XLA
#pragma unroll
        for (int j = 0; j < 8; ++j) {          // first-orig-index tie-break
          if (__float_as_uint(D[j].x) == g) best = min(best, (oidx[2*j]   << 13) | (base + 2*j));
          if (__float_as_uint(D[j].y) == g) best = min(best, (oidx[2*j+1] << 13) | (base + 2*j + 1));
        }
        atomicMin(&sm.f.idxsel[cur], best);
      }
      __syncthreads();                         // barrier 2: index final
      int packed = sm.f.idxsel[cur];
      packed = __builtin_amdgcn_readfirstlane(packed);
      float4 qv = pts4[packed & 8191];         // broadcast ds_read_b128 (sorted pos)
      qx = qv.x; qy = qv.y; qz = qv.z;
      if (tid == 0) {
        p1b[t*3+0] = qx; p1b[t*3+1] = qy; p1b[t*3+2] = qz;
        if ((t & 63) == 63)
          __hip_atomic_store(&prog[b], t, __ATOMIC_RELEASE, __HIP_MEMORY_SCOPE_AGENT);
      }
    }
    if (tid == 0)
      __hip_atomic_store(&prog[b], M_, __ATOMIC_RELEASE, __HIP_MEMORY_SCOPE_AGENT);
    return;
  }

  // ================= kNN + stats1 role (persistent consumer, unchanged) ============
  float4* tile = sm.k.tile;
  ull* mk = sm.k.mk;
  float* gfl = (float*)sm.k.tile;              // overlays tile after the scan phase
  float* bs = sm.k.bs;
  for (int ord = (int)blockIdx.x - B_; ord < 1024; ord += PERS) {
    const int b = ord & 3;                     // readiness-ordered chunks per block
    const int q0 = (ord >> 2) * 8;
    if (tid == 0) {
      while (__hip_atomic_load(&prog[b], __ATOMIC_ACQUIRE, __HIP_MEMORY_SCOPE_AGENT) < q0 + 7)
        __builtin_amdgcn_s_sleep(16);
    }
    __syncthreads();
    { int pv = __hip_atomic_load(&prog[b], __ATOMIC_ACQUIRE, __HIP_MEMORY_SCOPE_AGENT);
      asm volatile("" :: "v"(pv)); }           // per-thread acquire, kept live

    const int ql = (tid >> 5) & 7;             // query within block (tid<256 active)
    const int part = tid & 31;
    const int m = q0 + ql;
    const float* pb = p + (size_t)b*(N_*3);
    const float* qp_ = p1 + ((size_t)b*M_ + m)*3;
    float qx = qp_[0], qy = qp_[1], qz = qp_[2];
    float qq = __fadd_rn(__fadd_rn(__fmul_rn(qx,qx), __fmul_rn(qy,qy)), __fmul_rn(qz,qz));
    ull keys[20];
#pragma unroll
    for (int i = 0; i < 20; ++i) keys[i] = 0xFF8000007FFFFFFFull;  // pack(+inf, INT_MAX)
    float maxf = __uint_as_float(0x7F800000u);  // +inf
    for (int t0 = 0; t0 < N_; t0 += TILE_) {
      __syncthreads();                          // also guards gfl/tile reuse across chunks
      for (int i = tid; i < TILE_; i += 512) {
        float x = pb[(t0+i)*3+0], y = pb[(t0+i)*3+1], z = pb[(t0+i)*3+2];
        float pp = __fadd_rn(__fadd_rn(__fmul_rn(x,x), __fmul_rn(y,y)), __fmul_rn(z,z));
        tile[i] = make_float4(x, y, z, pp);
      }
      __syncthreads();
      if (tid < 256) {
        const int sbase = part * 32;
        for (int s = 0; s < 32; ++s) {
          int ss = sbase + ((s + part) & 31);   // bank skew across parts
          float4 pt = tile[ss];
          float qp = fmaf(pt.z, qz, fmaf(pt.y, qy, __fmul_rn(pt.x, qx)));
          float d = __fsub_rn(__fadd_rn(qq, pt.w), __fmul_rn(2.0f, qp));
          if (d <= maxf) {
            ull key = packkey(d, t0 + ss);
            if (key < keys[19]) { insert20(keys, key); maxf = keymaxf(keys[19]); }
          }
        }
      }
    }
    if (tid < 256) {
      ull* myslot = &mk[(ql*32 + part)*20];
#pragma unroll
      for (int i = 0; i < 20; ++i) myslot[i] = keys[i];
    }
    __syncthreads();
    if (tid < 256 && part == 0) {   // leader merges 32x20 sorted lists
      for (int pp2 = 1; pp2 < 32; ++pp2) {
        const ull* os = &mk[(ql*32 + pp2)*20];
        for (int i = 0; i < 20; ++i) {
          ull k = os[i];
          if (k >= keys[19]) break;    // sorted -> rest can't enter
          insert20(keys, k);
        }
      }
      ull* myslot = &mk[(ql*32)*20];
#pragma unroll
      for (int i = 0; i < 20; ++i) myslot[i] = keys[i];
    }
    __syncthreads();
    // gf write (global planes) + LDS stash for the stats1 tail
    for (int w = tid; w < 8*K_; w += 512) {
      int ql2 = w / K_;
      int kk = w - ql2*K_;
      ull key = mk[ql2*32*20 + kk];
      int idx = (int)(unsigned int)(key & 0xFFFFFFFFu);
      float gx = pb[idx*3+0], gy = pb[idx*3+1], gz = pb[idx*3+2];
      int m2 = q0 + ql2;
      const float* qv = p1 + ((size_t)b*M_ + m2)*3;
      size_t col = ((size_t)(b*M_ + m2))*K_ + kk;
      float d0 = __fsub_rn(gx, qv[0]);
      float d1 = __fsub_rn(gy, qv[1]);
      float d2 = __fsub_rn(gz, qv[2]);
      gfp[0*BMK + col] = d0;
      gfp[1*BMK + col] = d1;
      gfp[2*BMK + col] = d2;
      gfp[3*BMK + col] = gx;
      gfp[4*BMK + col] = gy;
      gfp[5*BMK + col] = gz;
      gfl[w*6+0] = d0; gfl[w*6+1] = d1; gfl[w*6+2] = d2;
      gfl[w*6+3] = gx; gfl[w*6+4] = gy; gfl[w*6+5] = gz;
    }
    __syncthreads();
    // stats1 tail: 8 grps x 64 lanes(=channels), 20 cols each (same fmaf sequence)
    {
      const int lane = tid & 63;
      const int grp = tid >> 6;
      float w1r[6];
#pragma unroll
      for (int c = 0; c < 6; ++c) w1r[c] = W1[lane*6 + c];
      float acc = 0.f, accq = 0.f;
      for (int cc = 0; cc < 20; ++cc) {
        const float* gv = &gfl[(grp*20 + cc)*6];
        float y = __fmul_rn(w1r[0], gv[0]);
#pragma unroll
        for (int c = 1; c < 6; ++c) y = fmaf(w1r[c], gv[c], y);
        float u = (y >= 0.f) ? y : 0.2f*y;
        acc += u;
        accq = fmaf(u, u, accq);
      }
      if (tid < 128) bs[tid] = 0.f;
      __syncthreads();
      atomicAdd(&bs[lane], acc);
      atomicAdd(&bs[64+lane], accq);
      __syncthreads();
      if (tid < 128) atomicAdd(&stats[tid], bs[tid]);
    }
  }
}

// BN coefficient replication (bit-identical to the old finalize_kernel)
__device__ __forceinline__ void bn_coeff(const float* __restrict__ st,
                                         const float* __restrict__ g,
                                         const float* __restrict__ bb,
                                         int o, float& A, float& C) {
  const float inv = 1.0f / (float)BMK;
  float mean = st[o] * inv;
  float var  = st[64+o] * inv - mean*mean;
  float a = g[o] / sqrtf(var + EPS_);
  A = a;
  C = fmaf(-a, mean, bb[o]);
}

// software grid barrier: all blocks co-resident (512 blocks x 4 waves << capacity)
__device__ __forceinline__ void gridbar(int* c, int expected) {
  __syncthreads();
  if (threadIdx.x == 0) {
    __hip_atomic_fetch_add(c, 1, __ATOMIC_ACQ_REL, __HIP_MEMORY_SCOPE_AGENT);
    while (__hip_atomic_load(c, __ATOMIC_ACQUIRE, __HIP_MEMORY_SCOPE_AGENT) < expected)
      __builtin_amdgcn_s_sleep(2);
  }
  __syncthreads();
}

// ---------- fused tail v2 (R13, unchanged) ----------
__global__ __launch_bounds__(256)
void tail_kernel(const float* __restrict__ gfp, const float* __restrict__ W1,
                 float* __restrict__ stats,
                 const float* __restrict__ g1, const float* __restrict__ b1,
                 const float* __restrict__ W2, float* __restrict__ u2t,
                 const float* __restrict__ W3,
                 const float* __restrict__ g2, const float* __restrict__ b2,
                 const float* __restrict__ g3, const float* __restrict__ b3,
                 float* __restrict__ out, int* __restrict__ bar,
                 float* __restrict__ pmx, float* __restrict__ pmn) {
  const int tid = threadIdx.x;
  const int nblk = (int)gridDim.x;
  const int lane = tid & 63;
  const int wid = ((int)blockIdx.x*256 + tid) >> 6;   // global wave id
  const int nw = (nblk*256) >> 6;                      // total waves (2048)
  __shared__ float sA[64], sC[64];
  __shared__ float bs[128];
  __shared__ float xbuf[4][64];                        // per-wave x1 broadcast slice
  float* xb = xbuf[(tid >> 6) & 3];

  // ---- phase A: convB (lane=channel) + fused stats2 ----
  {
    if (tid < 64) bn_coeff(stats, g1, b1, tid, sA[tid], sC[tid]);
    __syncthreads();
    float w1r[6];
#pragma unroll
    for (int c = 0; c < 6; ++c) w1r[c] = W1[lane*6 + c];
    const float sAl = sA[lane], sCl = sC[lane];
    float wrow[64];
#pragma unroll
    for (int c = 0; c < 64; ++c) wrow[c] = W2[lane*64 + c];
    float acc = 0.f, accq = 0.f;
    float gfn[6];
    int col = wid;
    if (col < BMK) {
#pragma unroll
      for (int c = 0; c < 6; ++c) gfn[c] = gfp[c*BMK + col];
    }
    for (; col < BMK; col += nw) {
      float gfc[6];
#pragma unroll
      for (int c = 0; c < 6; ++c) gfc[c] = gfn[c];
      if (col + nw < BMK) {                  // prefetch next col's gf
#pragma unroll
        for (int c = 0; c < 6; ++c) gfn[c] = gfp[c*BMK + (col + nw)];
      }
      // x1 for channel = lane (same fmaf sequence as original convB)
      float y = __fmul_rn(w1r[0], gfc[0]);
#pragma unroll
      for (int c = 1; c < 6; ++c) y = fmaf(w1r[c], gfc[c], y);
      float u = (y >= 0.f) ? y : 0.2f*y;
      float x1v = fmaf(sAl, u, sCl);
      xb[lane] = x1v;                        // intra-wave broadcast (lgkmcnt-ordered)
      float yo = 0.f;
      const float4* xb4 = (const float4*)xb;
#pragma unroll
      for (int c4 = 0; c4 < 16; ++c4) {      // c ascending 0..63, same order as before
        float4 v = xb4[c4];
        yo = fmaf(wrow[4*c4+0], v.x, yo);
        yo = fmaf(wrow[4*c4+1], v.y, yo);
        yo = fmaf(wrow[4*c4+2], v.z, yo);
        yo = fmaf(wrow[4*c4+3], v.w, yo);
      }
      float u2 = (yo >= 0.f) ? yo : 0.2f*yo;
      u2t[(size_t)col*64 + lane] = u2;       // coalesced 256B per wave
      acc += u2;
      accq = fmaf(u2, u2, accq);
    }
    if (tid < 128) bs[tid] = 0.f;
    __syncthreads();
    atomicAdd(&bs[lane], acc);
    atomicAdd(&bs[64+lane], accq);
    __syncthreads();
    if (tid < 128) atomicAdd(&stats[128 + tid], bs[tid]);
  }
  gridbar(&bar[0], nblk);

  // ---- phase B: stats3 sums + per-(b,m) min/max stash ----
  float w3[64];
  float bb = 0.f;
  {
    if (tid < 64) bn_coeff(stats + 128, g2, b2, tid, sA[tid], sC[tid]);
    __syncthreads();
#pragma unroll
    for (int c = 0; c < 64; ++c) w3[c] = W3[lane*64 + c] * sA[c];   // == W3f
#pragma unroll
    for (int c = 0; c < 64; ++c) bb = fmaf(W3[lane*64 + c], sC[c], bb);  // == b3f
    float acc = 0.f, accq = 0.f;
    for (int wv = wid; wv < B_*M_; wv += nw) {
      float mx = -3.4e38f, mn = 3.4e38f;
      for (int k = 0; k < K_; ++k) {
        const float4* u4 = (const float4*)(u2t + ((size_t)wv*K_ + k)*64);
        float y = bb;
#pragma unroll
        for (int c4 = 0; c4 < 16; ++c4) {
          float4 v = u4[c4];
          y = fmaf(w3[4*c4+0], v.x, y);
          y = fmaf(w3[4*c4+1], v.y, y);
          y = fmaf(w3[4*c4+2], v.z, y);
          y = fmaf(w3[4*c4+3], v.w, y);
        }
        float u = (y >= 0.f) ? y : 0.2f*y;
        acc += u; accq = fmaf(u, u, accq);
        mx = fmaxf(mx, u); mn = fminf(mn, u);
      }
      pmx[(size_t)wv*64 + lane] = mx;        // coalesced
      pmn[(size_t)wv*64 + lane] = mn;
    }
    if (tid < 128) bs[tid] = 0.f;
    __syncthreads();
    atomicAdd(&bs[lane], acc);
    atomicAdd(&bs[64+lane], accq);
    __syncthreads();
    if (tid < 128) atomicAdd(&stats[256 + tid], bs[tid]);
  }
  gridbar(&bar[1], nblk);

  // ---- phase C: BN3 finalize from stash ----
  {
    float A3, C3;
    bn_coeff(stats + 256, g3, b3, lane, A3, C3);
    for (int wv = wid; wv < B_*M_; wv += nw) {
      float mx = pmx[(size_t)wv*64 + lane];
      float mn = pmn[(size_t)wv*64 + lane];
      float r = (A3 >= 0.f) ? mx : mn;       // affine commutes with max when a>=0
      int b = wv >> 11, m = wv & 2047;
      out[((size_t)(b*64 + lane))*M_ + m] = fmaf(A3, r, C3);
    }
  }
}

// ---------- launch ----------
extern "C" void kernel_launch(void* const* d_in, const int* in_sizes, int n_in,
                              void* d_out, int out_size, void* d_ws, size_t ws_size,
                              hipStream_t stream) {
  const float* p  = (const float*)d_in[0];
  const float* W1 = (const float*)d_in[1];
  const float* g1 = (const float*)d_in[2];
  const float* b1 = (const float*)d_in[3];
  const float* W2 = (const float*)d_in[4];
  const float* g2 = (const float*)d_in[5];
  const float* b2 = (const float*)d_in[6];
  const float* W3 = (const float*)d_in[7];
  const float* g3 = (const float*)d_in[8];
  const float* b3 = (const float*)d_in[9];
  float* out = (float*)d_out;
  char* ws = (char*)d_ws;

  // workspace layout (~46.2 MB total)
  float* p1    = (float*)(ws);                 // 98,304 B   (dead after fpsknn)
  float* gfp   = (float*)(ws + 131072);        // 3,932,160 B (dead after tail phase A)
  float* u2t   = (float*)(ws + 4194304);       // 41,943,040 B
  float* stats = (float*)(ws + 46137344);      // 384 f (sum/sq x3 layers)
  int*   prog  = (int*)(ws + 46138880);        // 4 ints: fps progress per batch
  int*   bar   = (int*)(ws + 46138896);        // 3 ints: grid barrier counters
  // min/max stash (phase B->C) overlays the dead p1+gfp region: 2x 2MB within [0, 4MB)
  float* pmx   = (float*)(ws);                 // 2,097,152 B
  float* pmn   = (float*)(ws + 2097152);       // 2,097,152 B

  hipMemsetAsync((void*)stats, 0, 1568, stream);   // stats + prog + bar
  hipLaunchKernelGGL(fpsknn_kernel, dim3(B_ + PERS), dim3(512), 0, stream,
                     p, p1, gfp, W1, stats, prog);
  hipLaunchKernelGGL(tail_kernel,   dim3(512), dim3(256), 0, stream,
                     gfp, W1, stats, g1, b1, W2, u2t, W3, g2, b2, g3, b3, out, bar,
                     pmx, pmn);
}